// Round 5
// baseline (91.767 us; speedup 1.0000x reference)
//
#include <hip/hip_runtime.h>
#include <hip/hip_bf16.h>

#define B_  64
#define T_  2048
#define E_  512
#define Q_  1024
#define A_  128
#define C_  32
#define KW_ 31

using bf16x8 = __attribute__((ext_vector_type(8))) short;
using f32x4  = __attribute__((ext_vector_type(4))) float;

__device__ __forceinline__ short f2bf(float f) {
  union { float f; unsigned u; } x; x.f = f;
  unsigned r = x.u + 0x7fffu + ((x.u >> 16) & 1u);   // RNE
  return (short)(r >> 16);
}

__device__ __forceinline__ bf16x8 pack8(float4 a, float4 b) {
  union { bf16x8 v; __hip_bfloat162 h[4]; } u;
  u.h[0] = __float22bfloat162_rn(make_float2(a.x, a.y));
  u.h[1] = __float22bfloat162_rn(make_float2(a.z, a.w));
  u.h[2] = __float22bfloat162_rn(make_float2(b.x, b.y));
  u.h[3] = __float22bfloat162_rn(make_float2(b.z, b.w));
  return u.v;
}

__device__ __forceinline__ float fast_tanh(float x) {
  float e2 = __expf(2.f * x);
  return 1.f - 2.f * __builtin_amdgcn_rcpf(e2 + 1.f);
}

__device__ __forceinline__ void gload16(const void* g, void* l) {
  __builtin_amdgcn_global_load_lds(
      (const __attribute__((address_space(1))) unsigned int*)g,
      (__attribute__((address_space(3))) unsigned int*)l, 16, 0, 0);
}

// ---------------- prep: q2 partials (b x 8 K-slices); Wk,Wloc -> MFMA B-frag order (bf16)
__global__ __launch_bounds__(256) void prep_kernel(
    const float* __restrict__ dh, const float* __restrict__ Wq,
    const float* __restrict__ conv_b, const float* __restrict__ Wloc,
    const float* __restrict__ Wk,
    unsigned short* __restrict__ wkf, unsigned short* __restrict__ wlocf,
    float* __restrict__ q2p)
{
  int blk = blockIdx.x;
  int tid = threadIdx.x;
  if (blk < 512) {
    __shared__ float part[128];
    int b = blk >> 3, kq = blk & 7;
    int a = tid & 127, kh = tid >> 7;
    const float* dhr = dh + b * Q_ + kq * 128 + kh * 64;
    const float* wq  = Wq + (size_t)(kq * 128 + kh * 64) * A_ + a;
    float s = 0.f;
    #pragma unroll 8
    for (int k = 0; k < 64; ++k) s += dhr[k] * wq[(size_t)k * A_];
    if (kh) part[a] = s;
    __syncthreads();
    if (!kh) {
      s += part[a];
      if (kq == 0) {
        float t = 0.f;
        #pragma unroll 8
        for (int c = 0; c < C_; ++c) t += conv_b[c] * Wloc[c * A_ + a];
        s += t;
      }
      q2p[(kq * B_ + b) * A_ + a] = s;
    }
  } else if (blk < 544) {
    int wave = tid >> 6, lane = tid & 63;
    int g = (blk - 512) * 4 + wave;          // 0..127
    int ks = g >> 3, nt = g & 7;
    int lg = lane >> 4, lr = lane & 15;
    bf16x8 o;
    #pragma unroll
    for (int j = 0; j < 8; ++j)
      o[j] = f2bf(Wk[(ks * 32 + lg * 8 + j) * A_ + nt * 16 + lr]);
    *(bf16x8*)(wkf + ((size_t)g * 64 + lane) * 8) = o;
  } else {
    int wave = tid >> 6, lane = tid & 63;
    int g = (blk - 544) * 4 + wave;          // 0..7
    int lg = lane >> 4, lr = lane & 15;
    bf16x8 o;
    #pragma unroll
    for (int j = 0; j < 8; ++j)
      o[j] = f2bf(Wloc[(lg * 8 + j) * A_ + g * 16 + lr]);
    *(bf16x8*)(wlocf + ((size_t)g * 64 + lane) * 8) = o;
  }
}

// ---------------- energy: out = exp(v . tanh(enc@Wk + q2[b] + conv(prev)@Wloc)), psum partials
// A-loads issued as 2-K-step bursts (256-B runs per row) for DRAM page locality;
// B staged via global_load_lds double-buffer; counted vmcnt(8)/vmcnt(0) protocol.
__global__ __launch_bounds__(256, 3) void energy_kernel(
    const float* __restrict__ enc, const float* __restrict__ prev,
    const float* __restrict__ conv_w,
    const unsigned short* __restrict__ wkfall,   // wkf slices 0..15, wlocf = slice 16
    const float* __restrict__ q2p, const float* __restrict__ vvec,
    float* __restrict__ outexp, float* __restrict__ psum)
{
  __shared__ unsigned short sB0[4096];   // 8 KB double buffer for B frags
  __shared__ unsigned short sB1[4096];
  __shared__ float sprev[160];
  __shared__ float scw[KW_][C_];
  __shared__ unsigned short slocb[128][C_];
  __shared__ float swsum[4];

  int tid = threadIdx.x;
  int m0 = blockIdx.x * 128;
  int b  = m0 >> 11, t0 = m0 & (T_ - 1);

  int wave = tid >> 6, lane = tid & 63;
  int lg = lane >> 4, lr = lane & 15;
  int wm = m0 + wave * 32;

  const float* encRow0 = enc + (size_t)(wm + lr) * E_ + lg * 8;
  const float* encRow1 = encRow0 + 16 * E_;

  #define STAGE(slice, buf) do {                                              \
    const unsigned short* s_ = wkfall + (size_t)(slice) * 4096 + wave * 512 + lane * 8; \
    gload16(s_,        &buf[wave * 512]);                                     \
    gload16(s_ + 2048, &buf[(4 + wave) * 512]);                               \
  } while (0)

  // ---- issue first B-stage + first A-burst (ks 0,1) BEFORE conv preamble
  float4 fl0, fl1, fl2, fl3, fl4, fl5, fl6, fl7;
  STAGE(0, sB0);
  __builtin_amdgcn_sched_barrier(0);
  fl0 = *(const float4*)(encRow0);      fl1 = *(const float4*)(encRow0 + 4);
  fl4 = *(const float4*)(encRow0 + 32); fl5 = *(const float4*)(encRow0 + 36);
  fl2 = *(const float4*)(encRow1);      fl3 = *(const float4*)(encRow1 + 4);
  fl6 = *(const float4*)(encRow1 + 32); fl7 = *(const float4*)(encRow1 + 36);
  __builtin_amdgcn_sched_barrier(0);

  // ---- conv preamble (overlaps the in-flight loads)
  for (int i = tid; i < 158; i += 256) {
    int t = t0 - 15 + i;
    sprev[i] = (t >= 0 && t < T_) ? prev[b * T_ + t] : 0.f;
  }
  for (int i = tid; i < KW_ * C_; i += 256) {
    int j = i >> 5, c = i & 31;
    scw[j][c] = conv_w[c * KW_ + j];
  }
  __syncthreads();
  {
    int tl = tid >> 1, ch0 = (tid & 1) * 16;
    float acc[16];
    #pragma unroll
    for (int c = 0; c < 16; ++c) acc[c] = 0.f;
    for (int j = 0; j < KW_; ++j) {
      float p = sprev[tl + j];
      #pragma unroll
      for (int c = 0; c < 16; ++c) acc[c] += p * scw[j][ch0 + c];
    }
    unsigned int* dstp = (unsigned int*)&slocb[tl][ch0];
    #pragma unroll
    for (int c = 0; c < 16; c += 2)
      dstp[c >> 1] = ((unsigned int)(unsigned short)f2bf(acc[c + 1]) << 16)
                   | (unsigned short)f2bf(acc[c]);
  }
  __syncthreads();   // full drain: sB0 staged, fl0..7 landed, slocb ready

  f32x4 acc0[8], acc1[8];
  #pragma unroll
  for (int i = 0; i < 8; ++i) { acc0[i] = (f32x4){0,0,0,0}; acc1[i] = (f32x4){0,0,0,0}; }

  #pragma unroll 1
  for (int i = 0; i < 8; ++i) {
    // convert the landed burst (ks=2i, 2i+1) to bf16 fragments
    bf16x8 af00 = pack8(fl0, fl1), af01 = pack8(fl2, fl3);
    bf16x8 af10 = pack8(fl4, fl5), af11 = pack8(fl6, fl7);

    // ---- even half (ks=2i): stage B slice 2i+1, burst A for ks 2i+2,2i+3
    STAGE(2 * i + 1, sB1);
    __builtin_amdgcn_sched_barrier(0);       // pin: stage older than burst
    if (i < 7) {
      const float* r0 = encRow0 + (2 * i + 2) * 32;
      const float* r1 = encRow1 + (2 * i + 2) * 32;
      fl0 = *(const float4*)(r0);      fl1 = *(const float4*)(r0 + 4);
      fl4 = *(const float4*)(r0 + 32); fl5 = *(const float4*)(r0 + 36);
      fl2 = *(const float4*)(r1);      fl3 = *(const float4*)(r1 + 4);
      fl6 = *(const float4*)(r1 + 32); fl7 = *(const float4*)(r1 + 36);
    }
    __builtin_amdgcn_sched_barrier(0);
    #pragma unroll
    for (int nt = 0; nt < 8; ++nt) {
      bf16x8 bfr = *(const bf16x8*)&sB0[nt * 512 + lane * 8];
      acc0[nt] = __builtin_amdgcn_mfma_f32_16x16x32_bf16(af00, bfr, acc0[nt], 0, 0, 0);
      acc1[nt] = __builtin_amdgcn_mfma_f32_16x16x32_bf16(af01, bfr, acc1[nt], 0, 0, 0);
    }
    if (i < 7) { asm volatile("s_waitcnt vmcnt(8) lgkmcnt(0)" ::: "memory"); }
    else       { asm volatile("s_waitcnt vmcnt(0) lgkmcnt(0)" ::: "memory"); }
    __builtin_amdgcn_sched_barrier(0);
    __builtin_amdgcn_s_barrier();

    // ---- odd half (ks=2i+1): stage B slice 2i+2 into sB0 (slice 16 = wlocf)
    STAGE(2 * i + 2, sB0);
    __builtin_amdgcn_sched_barrier(0);
    #pragma unroll
    for (int nt = 0; nt < 8; ++nt) {
      bf16x8 bfr = *(const bf16x8*)&sB1[nt * 512 + lane * 8];
      acc0[nt] = __builtin_amdgcn_mfma_f32_16x16x32_bf16(af10, bfr, acc0[nt], 0, 0, 0);
      acc1[nt] = __builtin_amdgcn_mfma_f32_16x16x32_bf16(af11, bfr, acc1[nt], 0, 0, 0);
    }
    asm volatile("s_waitcnt vmcnt(0) lgkmcnt(0)" ::: "memory");
    __builtin_amdgcn_sched_barrier(0);
    __builtin_amdgcn_s_barrier();
  }

  { // location term: slice 16 (wlocf) in sB0; A from slocb
    int lrow = wave * 32 + lr;
    bf16x8 af0 = *(const bf16x8*)&slocb[lrow][lg * 8];
    bf16x8 af1 = *(const bf16x8*)&slocb[lrow + 16][lg * 8];
    #pragma unroll
    for (int nt = 0; nt < 8; ++nt) {
      bf16x8 bfr = *(const bf16x8*)&sB0[nt * 512 + lane * 8];
      acc0[nt] = __builtin_amdgcn_mfma_f32_16x16x32_bf16(af0, bfr, acc0[nt], 0, 0, 0);
      acc1[nt] = __builtin_amdgcn_mfma_f32_16x16x32_bf16(af1, bfr, acc1[nt], 0, 0, 0);
    }
  }

  // epilogue: qv = sum of 8 q2 partials; p = v.tanh(acc+qv); out = exp(p); psum partial
  float qv[8], vv[8];
  #pragma unroll
  for (int nt = 0; nt < 8; ++nt) {
    int n = nt * 16 + lr;
    float s = 0.f;
    #pragma unroll
    for (int p = 0; p < 8; ++p) s += q2p[(p * B_ + b) * A_ + n];
    qv[nt] = s;
    vv[nt] = vvec[n];
  }
  float ssum = 0.f;
  #pragma unroll
  for (int f = 0; f < 2; ++f) {
    f32x4* acc = f ? acc1 : acc0;
    float p0 = 0, p1 = 0, p2 = 0, p3 = 0;
    #pragma unroll
    for (int nt = 0; nt < 8; ++nt) {
      p0 += fast_tanh(acc[nt][0] + qv[nt]) * vv[nt];
      p1 += fast_tanh(acc[nt][1] + qv[nt]) * vv[nt];
      p2 += fast_tanh(acc[nt][2] + qv[nt]) * vv[nt];
      p3 += fast_tanh(acc[nt][3] + qv[nt]) * vv[nt];
    }
    #pragma unroll
    for (int off = 1; off < 16; off <<= 1) {
      p0 += __shfl_xor(p0, off, 64);
      p1 += __shfl_xor(p1, off, 64);
      p2 += __shfl_xor(p2, off, 64);
      p3 += __shfl_xor(p3, off, 64);
    }
    float e0 = __expf(p0), e1 = __expf(p1), e2 = __expf(p2), e3 = __expf(p3);
    ssum += (e0 + e1) + (e2 + e3);
    if (lr == 0)
      *(float4*)(outexp + wm + f * 16 + lg * 4) = make_float4(e0, e1, e2, e3);
  }
  ssum += __shfl_xor(ssum, 16, 64);
  ssum += __shfl_xor(ssum, 32, 64);
  if (lane == 0) swsum[wave] = ssum;
  __syncthreads();
  if (tid == 0)
    psum[b * 16 + (blockIdx.x & 15)] = (swsum[0] + swsum[1]) + (swsum[2] + swsum[3]);
}

// ---------------- normalize: out[b,:] *= 1/sum(psum[b,:])
__global__ __launch_bounds__(256) void norm_kernel(float* __restrict__ out,
                                                   const float* __restrict__ psum)
{
  int b = blockIdx.x, tid = threadIdx.x;
  float s = 0.f;
  #pragma unroll
  for (int p = 0; p < 16; ++p) s += psum[b * 16 + p];
  float inv = 1.f / s;
  float4* row = (float4*)(out + (size_t)b * T_);
  #pragma unroll
  for (int j = 0; j < 2; ++j) {
    float4 x = row[tid + j * 256];
    x.x *= inv; x.y *= inv; x.z *= inv; x.w *= inv;
    row[tid + j * 256] = x;
  }
}

extern "C" void kernel_launch(void* const* d_in, const int* in_sizes, int n_in,
                              void* d_out, int out_size, void* d_ws, size_t ws_size,
                              hipStream_t stream)
{
  const float* enc   = (const float*)d_in[0];
  const float* dh    = (const float*)d_in[1];
  const float* prev  = (const float*)d_in[2];
  const float* Wq    = (const float*)d_in[3];
  const float* Wk    = (const float*)d_in[4];
  const float* convw = (const float*)d_in[5];
  const float* convb = (const float*)d_in[6];
  const float* Wloc  = (const float*)d_in[7];
  const float* v     = (const float*)d_in[8];
  float* out = (float*)d_out;

  char* w = (char*)d_ws;
  unsigned short* wkf   = (unsigned short*)w;               // 16 slices x 8 KB = 131072 B
  unsigned short* wlocf = (unsigned short*)(w + 131072);    // slice 16, 8192 B (contiguous)
  float*          q2p   = (float*)(w + 139264);             // 8*64*128 f32 = 262144 B
  float*          psum  = (float*)(w + 401408);             // 64*16 f32 = 4096 B

  hipLaunchKernelGGL(prep_kernel, dim3(546), dim3(256), 0, stream,
                     dh, Wq, convb, Wloc, Wk, wkf, wlocf, q2p);
  hipLaunchKernelGGL(energy_kernel, dim3(1024), dim3(256), 0, stream,
                     enc, prev, convw, wkf, q2p, v, out, psum);
  hipLaunchKernelGGL(norm_kernel, dim3(64), dim3(256), 0, stream, out, psum);
}